// Round 1
// baseline (221.549 us; speedup 1.0000x reference)
//
#include <hip/hip_runtime.h>
#include <hip/hip_bf16.h>
#include <stdint.h>

typedef short bf16x8 __attribute__((ext_vector_type(8)));
typedef float f32x4  __attribute__((ext_vector_type(4)));

#define NB   8
#define NC   256
#define NO   256
#define HH   64
#define WW   64
#define NPIX 4096
#define KTOT 2304
#define NKC  72

// workspace layout (bytes)
#define XN_OFF  0u
#define XN_SZ   (NB*NPIX*NC*2u)        // 16,777,216  x in NHWC bf16
#define WP_OFF  (XN_OFF + XN_SZ)
#define WP_SZ   (KTOT*NO*2u)           // 1,179,648   main weights, frag order
#define WPO_OFF (WP_OFF + WP_SZ)
#define WPO_SZ  (KTOT*32u*2u)          // 147,456     offset-conv weights, frag order
#define OM_OFF  (WPO_OFF + WPO_SZ)
#define OM_SZ   (NB*NPIX*32u*4u)       // 4,194,304   offset-conv output [b][pix][32]
#define PY_OFF  (OM_OFF + OM_SZ)
#define CO_SZ   (NB*9u*NPIX*4u)        // 1,179,648 each
#define PX_OFF  (PY_OFF + CO_SZ)
#define MK_OFF  (PX_OFF + CO_SZ)

__device__ __forceinline__ float b2f(short s) {
    union { unsigned u; float f; } z; z.u = ((unsigned)(unsigned short)s) << 16; return z.f;
}
__device__ __forceinline__ short f2b(float f) {
    __hip_bfloat16 h = __float2bfloat16(f);
    short s; __builtin_memcpy(&s, &h, 2); return s;
}

// ---------------- kernel 1: x (NCHW f32) -> xn (NHWC bf16) ----------------
__global__ void pack_x(const float* __restrict__ x, unsigned short* __restrict__ xn) {
    __shared__ float tile[64][65];
    int blk = blockIdx.x;
    int pt = blk & 63, ct = (blk >> 6) & 3, b = blk >> 8;
    int t = threadIdx.x;
    int pi = t & 63, ci0 = t >> 6;
    const float* src = x + ((size_t)(b*NC + ct*64))*NPIX + (size_t)pt*64;
#pragma unroll
    for (int j = 0; j < 16; ++j)
        tile[ci0 + 4*j][pi] = src[(size_t)(ci0 + 4*j)*NPIX + pi];
    __syncthreads();
    int c = t & 63, pj0 = t >> 6;
    unsigned short* dst = xn + ((size_t)b*NPIX + (size_t)pt*64)*NC + ct*64;
#pragma unroll
    for (int j = 0; j < 16; ++j) {
        int pj = pj0 + 4*j;
        dst[(size_t)pj*NC + c] = (unsigned short)f2b(tile[c][pj]);
    }
}

// ---------------- kernel 2: pack main weight into B-fragment order ----------------
// layout: flat = ((kc*16 + nt)*64 + lane)*8 + e ; value = W[k][o], k = kc*32 + 8*(lane>>4) + e
// K order: k = k2*256 + c (k2 = ky*3+kx outer, channel inner)
__global__ void pack_w(const float* __restrict__ weight, unsigned short* __restrict__ wp) {
    int idx = blockIdx.x*256 + threadIdx.x;           // 589,824 total
    int e = idx & 7, l = (idx >> 3) & 63, nt = (idx >> 9) & 15, kc = idx >> 13;
    int k  = kc*32 + 8*(l >> 4) + e;
    int k2 = k >> 8, c = k & 255;
    int ky = k2 / 3, kx = k2 - 3*ky;
    int o  = nt*16 + (l & 15);
    float v = weight[(size_t)(o*NC + c)*9 + ky*3 + kx];
    wp[idx] = (unsigned short)f2b(v);
}

// ---------------- kernel 3: pack offset-conv weight (N padded 27->32) ----------------
__global__ void pack_wo(const float* __restrict__ w_off, unsigned short* __restrict__ wpo) {
    int idx = blockIdx.x*256 + threadIdx.x;           // 73,728 total
    int e = idx & 7, l = (idx >> 3) & 63, nt = (idx >> 9) & 1, kc = idx >> 10;
    int k  = kc*32 + 8*(l >> 4) + e;
    int k2 = k >> 8, c = k & 255;
    int ky = k2 / 3, kx = k2 - 3*ky;
    int n  = nt*16 + (l & 15);
    float v = (n < 27) ? w_off[(size_t)(n*NC + c)*9 + ky*3 + kx] : 0.0f;
    wpo[idx] = (unsigned short)f2b(v);
}

// ---------------- kernel 4: offset conv (implicit GEMM, M=64/block, N=32) ----------------
__launch_bounds__(256, 2)
__global__ void off_conv(const unsigned short* __restrict__ xn,
                         const unsigned short* __restrict__ wpo,
                         float* __restrict__ om) {
    int blk = blockIdx.x;                 // 512 = 8 b * 64 mtiles
    int mt = blk & 63, b = blk >> 6;
    int t = threadIdx.x, wv = t >> 6, l = t & 63, g = l >> 4;
    int pix = mt*64 + wv*16 + (l & 15);
    int y = pix >> 6, xx = pix & 63;
    f32x4 acc0 = {0.f,0.f,0.f,0.f}, acc1 = {0.f,0.f,0.f,0.f};
    const unsigned short* xb = xn + (size_t)b*NPIX*NC;
    const bf16x8* wpf = (const bf16x8*)wpo;
    for (int kc = 0; kc < NKC; ++kc) {
        int k2 = kc >> 3, cc = kc & 7;
        int ky = k2 / 3, kx = k2 - 3*ky;
        int sy = y + ky - 1, sx = xx + kx - 1;
        bool valid = (sy >= 0) & (sy < HH) & (sx >= 0) & (sx < WW);
        bf16x8 a = {0,0,0,0,0,0,0,0};
        if (valid)
            a = *(const bf16x8*)(xb + (size_t)(sy*WW + sx)*NC + cc*32 + g*8);
        bf16x8 b0 = wpf[(size_t)(kc*2    )*64 + l];
        bf16x8 b1 = wpf[(size_t)(kc*2 + 1)*64 + l];
        acc0 = __builtin_amdgcn_mfma_f32_16x16x32_bf16(a, b0, acc0, 0, 0, 0);
        acc1 = __builtin_amdgcn_mfma_f32_16x16x32_bf16(a, b1, acc1, 0, 0, 0);
    }
#pragma unroll
    for (int r = 0; r < 4; ++r) {
        int pm = mt*64 + wv*16 + 4*g + r;
        om[((size_t)b*NPIX + pm)*32 +      (l & 15)] = acc0[r];
        om[((size_t)b*NPIX + pm)*32 + 16 + (l & 15)] = acc1[r];
    }
}

// ---------------- kernel 5: om -> sampling coords (py, px, mask) ----------------
__global__ void coords_k(const float* __restrict__ om, const float* __restrict__ b_off,
                         float* __restrict__ py, float* __restrict__ px,
                         float* __restrict__ mk) {
    int idx = blockIdx.x*256 + threadIdx.x;       // 294,912 = 8*9*4096
    if (idx >= NB*9*NPIX) return;
    int pix = idx & 4095;
    int k   = (idx >> 12) % 9;
    int b   = idx / (9*NPIX);
    const float* omp = om + ((size_t)b*NPIX + pix)*32;
    float dy = omp[2*k]     + b_off[2*k];
    float dx = omp[2*k + 1] + b_off[2*k + 1];
    float m  = omp[18 + k]  + b_off[18 + k];
    float yy = (float)(pix >> 6) - 1.0f + (float)(k / 3) + dy;
    float xv = (float)(pix & 63) - 1.0f + (float)(k % 3) + dx;
    py[idx] = yy;
    px[idx] = xv;
    mk[idx] = 1.0f / (1.0f + __expf(-m));
}

// ---------------- kernel 6: main deformable conv (implicit GEMM + on-the-fly bilinear A) --
// block: 4 waves, M-tile 64 (16 pix/wave), N full 256 (16 frags/wave), K loop 72 x 32
__launch_bounds__(256, 2)
__global__ void dcn_main(const unsigned short* __restrict__ xn,
                         const unsigned short* __restrict__ wpack,
                         const float* __restrict__ pyA,
                         const float* __restrict__ pxA,
                         const float* __restrict__ mkA,
                         const float* __restrict__ bias,
                         float* __restrict__ out) {
    __shared__ unsigned short lds[2][8192];       // 2 x 16 KB K-chunk of W
    int blk = blockIdx.x;                         // 512 = 8 b * 64 mtiles
    int mt = blk & 63, b = blk >> 6;
    int t = threadIdx.x, wv = t >> 6, l = t & 63, g = l >> 4;
    int pixm = mt*64 + wv*16 + (l & 15);          // this lane's A-row pixel

    f32x4 acc[16];
#pragma unroll
    for (int i = 0; i < 16; ++i) acc[i] = f32x4{0.f,0.f,0.f,0.f};

    const unsigned short* xb = xn + (size_t)b*NPIX*NC;

#define STAGE(bi, kcs) do {                                                            \
        const unsigned short* _gs = wpack + (size_t)(kcs)*8192 + wv*2048 + l*8;        \
        _Pragma("unroll")                                                              \
        for (int _i = 0; _i < 4; ++_i) {                                               \
            __builtin_amdgcn_global_load_lds(                                          \
                (const __attribute__((address_space(1))) unsigned int*)(_gs + _i*512), \
                (__attribute__((address_space(3))) unsigned int*)(&lds[bi][wv*2048 + _i*512]), \
                16, 0, 0);                                                             \
        }                                                                              \
    } while (0)

    float cw0 = 0.f, cw1 = 0.f, cw2 = 0.f, cw3 = 0.f;
    unsigned ca0 = 0, ca1 = 0, ca2 = 0, ca3 = 0;

    STAGE(0, 0);
    __syncthreads();
    int buf = 0;
    for (int kc = 0; kc < NKC; ++kc) {
        int k2 = kc >> 3, cc = kc & 7;
        if (cc == 0) {
            int ci = ((b*9 + k2) << 12) + pixm;
            float py = pyA[ci], px = pxA[ci], m = mkA[ci];
            float y0f = floorf(py), x0f = floorf(px);
            float ly = py - y0f, lx = px - x0f;
            int iy0 = (int)y0f, ix0 = (int)x0f;
            int iy1 = iy0 + 1,  ix1 = ix0 + 1;
            bool vy0 = (iy0 >= 0) & (iy0 < HH);
            bool vy1 = (iy1 >= 0) & (iy1 < HH);
            bool vx0 = (ix0 >= 0) & (ix0 < WW);
            bool vx1 = (ix1 >= 0) & (ix1 < WW);
            float wy0 = (1.f - ly) * m, wy1 = ly * m;
            cw0 = (vy0 & vx0) ? wy0 * (1.f - lx) : 0.f;
            cw1 = (vy0 & vx1) ? wy0 * lx         : 0.f;
            cw2 = (vy1 & vx0) ? wy1 * (1.f - lx) : 0.f;
            cw3 = (vy1 & vx1) ? wy1 * lx         : 0.f;
            int cy0 = min(max(iy0, 0), HH-1), cy1 = min(max(iy1, 0), HH-1);
            int cx0 = min(max(ix0, 0), WW-1), cx1 = min(max(ix1, 0), WW-1);
            ca0 = (unsigned)(((cy0*WW + cx0)*NC + g*8) * 2);
            ca1 = (unsigned)(((cy0*WW + cx1)*NC + g*8) * 2);
            ca2 = (unsigned)(((cy1*WW + cx0)*NC + g*8) * 2);
            ca3 = (unsigned)(((cy1*WW + cx1)*NC + g*8) * 2);
        }
        if (kc < NKC-1) STAGE(buf ^ 1, kc + 1);

        unsigned co = (unsigned)cc * 64u;         // channel byte offset within k2
        const char* xc = (const char*)xb;
        bf16x8 v00 = *(const bf16x8*)(xc + ca0 + co);
        bf16x8 v01 = *(const bf16x8*)(xc + ca1 + co);
        bf16x8 v10 = *(const bf16x8*)(xc + ca2 + co);
        bf16x8 v11 = *(const bf16x8*)(xc + ca3 + co);
        bf16x8 a;
#pragma unroll
        for (int e = 0; e < 8; ++e) {
            float f = cw0*b2f(v00[e]) + cw1*b2f(v01[e]) + cw2*b2f(v10[e]) + cw3*b2f(v11[e]);
            a[e] = f2b(f);
        }
        const bf16x8* bl = (const bf16x8*)&lds[buf][0];
#pragma unroll
        for (int nt = 0; nt < 16; ++nt)
            acc[nt] = __builtin_amdgcn_mfma_f32_16x16x32_bf16(a, bl[nt*64 + l], acc[nt], 0, 0, 0);
        __syncthreads();
        buf ^= 1;
    }
#undef STAGE

    int pm = mt*64 + wv*16 + 4*g;
#pragma unroll
    for (int nt = 0; nt < 16; ++nt) {
        int o = nt*16 + (l & 15);
        float bv = bias[o];
        f32x4 r = acc[nt] + bv;
        *(f32x4*)(out + ((size_t)(b*NO + o))*NPIX + pm) = r;
    }
}

extern "C" void kernel_launch(void* const* d_in, const int* in_sizes, int n_in,
                              void* d_out, int out_size, void* d_ws, size_t ws_size,
                              hipStream_t stream) {
    const float* x      = (const float*)d_in[0];
    const float* weight = (const float*)d_in[1];
    const float* bias   = (const float*)d_in[2];
    const float* w_off  = (const float*)d_in[3];
    const float* b_off  = (const float*)d_in[4];
    float* out = (float*)d_out;
    char* ws = (char*)d_ws;

    unsigned short* xn  = (unsigned short*)(ws + XN_OFF);
    unsigned short* wp  = (unsigned short*)(ws + WP_OFF);
    unsigned short* wpo = (unsigned short*)(ws + WPO_OFF);
    float* om = (float*)(ws + OM_OFF);
    float* py = (float*)(ws + PY_OFF);
    float* px = (float*)(ws + PX_OFF);
    float* mk = (float*)(ws + MK_OFF);

    pack_x  <<<2048, 256, 0, stream>>>(x, xn);
    pack_w  <<<KTOT*NO/256,  256, 0, stream>>>(weight, wp);    // 2304 blocks
    pack_wo <<<KTOT*32/256,  256, 0, stream>>>(w_off, wpo);    // 288 blocks
    off_conv<<<512, 256, 0, stream>>>(xn, wpo, om);
    coords_k<<<NB*9*NPIX/256, 256, 0, stream>>>(om, b_off, py, px, mk); // 1152 blocks
    dcn_main<<<512, 256, 0, stream>>>(xn, wp, py, px, mk, bias, out);
}